// Round 1
// 12896.332 us; speedup vs baseline: 1.1662x; 1.1662x over previous
//
#include <hip/hip_runtime.h>
#include <hip/hip_bf16.h>

// ---------------- types ----------------
typedef _Float16 half2_t __attribute__((ext_vector_type(2)));
typedef _Float16 half8_t __attribute__((ext_vector_type(8)));
typedef float float4_t __attribute__((ext_vector_type(4)));
typedef unsigned uint4_t __attribute__((ext_vector_type(4)));

#define SEQ   8192
#define ISZ   512
#define HID   2048
#define G4H   8192   // 4*HID
#define NB    256    // persistent blocks (== CU count)
#define NREP  8      // replication of published h-words (readers/line: 256 -> 32)

#if __has_builtin(__builtin_amdgcn_fdot2)
#define DOT2(a, b, c) __builtin_amdgcn_fdot2((a), (b), (c), false)
#else
static __device__ __forceinline__ float DOT2(half2_t a, half2_t b, float c) {
    return c + (float)a.x * (float)b.x + (float)a.y * (float)b.y;
}
#endif

#if __has_builtin(__builtin_amdgcn_rcpf)
#define RCP(x) __builtin_amdgcn_rcpf(x)
#else
#define RCP(x) (1.0f / (x))
#endif

// relaxed agent-scope (sc1, device-coherent) store — no fences, no RMW
static __device__ __forceinline__ void st_u64(void* p, unsigned long long v) {
    __hip_atomic_store((unsigned long long*)p, v, __ATOMIC_RELAXED,
                       __HIP_MEMORY_SCOPE_AGENT);
}

// Wide agent-coherent poll: 32 B of one 64-B line as 2 x dwordx4 with sc1
// (same L2-bypass bit __hip_atomic_load(AGENT) lowers to). Each 8-B word is
// 16-B-aligned within a single line access => never torn; tags are per-word
// self-validating so skew between the two loads is harmless.
static __device__ __forceinline__ void poll_load32(const void* p, uint4_t& a,
                                                   uint4_t& b) {
    unsigned long long addr = (unsigned long long)p;
    asm volatile(
        "global_load_dwordx4 %0, %2, off sc1\n\t"
        "global_load_dwordx4 %1, %2, off offset:16 sc1\n\t"
        "s_waitcnt vmcnt(0)"
        : "=&v"(a), "=&v"(b)
        : "v"(addr)
        : "memory");
}

// DPP butterfly add: x + perm(x). Valid for reduction levels where the
// permutation crosses the current group boundary (see call sites).
template <int CTRL>
static __device__ __forceinline__ float dpp_add(float x) {
    int v = __builtin_amdgcn_update_dpp(0, __builtin_bit_cast(int, x), CTRL, 0xF,
                                        0xF, true);
    return x + __builtin_bit_cast(float, v);
}
// DPP move (no add): lane i <- lane i+N (row_shl:N), zeros past row edge.
template <int CTRL>
static __device__ __forceinline__ float dpp_movf(float x) {
    int v = __builtin_amdgcn_update_dpp(0, __builtin_bit_cast(int, x), CTRL, 0xF,
                                        0xF, true);
    return __builtin_bit_cast(float, v);
}
#define DPP_XOR1  0xB1   // quad_perm [1,0,3,2]
#define DPP_XOR2  0x4E   // quad_perm [2,3,0,1]
#define DPP_XOR4  0x141  // row_half_mirror (valid: groups of 4 uniform)
#define DPP_XOR8  0x128  // row_ror:8 (exact lane s <-> s+8 within row16)
#define DPP_SHL1  0x101  // row_shl:1
#define DPP_SHL2  0x102  // row_shl:2
#define DPP_SHL4  0x104  // row_shl:4
#define DPP_SHL6  0x106  // row_shl:6

// ---------------- f32 -> f16 convert ----------------
__global__ __launch_bounds__(256) void cvt_f32_f16(const float* __restrict__ in,
                                                   _Float16* __restrict__ out, int n) {
    int i = (blockIdx.x * 256 + threadIdx.x) * 4;
    if (i < n) {
        float4 v = *(const float4*)(in + i);
        out[i + 0] = (_Float16)v.x;
        out[i + 1] = (_Float16)v.y;
        out[i + 2] = (_Float16)v.z;
        out[i + 3] = (_Float16)v.w;
    }
}

// ---------------- init words (zero => {h=0, tag=0} == "h_0 valid") ----------------
__global__ __launch_bounds__(256) void init_state(unsigned long long* __restrict__ words) {
    int i = blockIdx.x * 256 + threadIdx.x;
    if (i < 2 * NREP * 2048) words[i] = 0ull;  // words[2][NREP][256][8]
}

// ---------------- x_proj GEMM: C = A @ B^T, epilogue scattered into xp2 ----------
// xp2 layout: xp2[t][b*32 + g*8 + r] where r = gate*2 + (elem&1), g = (elem>>1)&3,
// b = elem>>3  (elem = col & 2047, gate = col >> 11). One 64-B line per block-step.
__global__ __launch_bounds__(256) void gemm_xproj(const _Float16* __restrict__ A,  // [SEQ][ISZ]
                                                  const _Float16* __restrict__ B,  // [G4H][ISZ]
                                                  _Float16* __restrict__ C) {      // [SEQ][G4H] permuted
    __shared__ _Float16 As[128 * 40];
    __shared__ _Float16 Bs[128 * 40];
    const int tid = threadIdx.x;
    const int bm = blockIdx.y, bn = blockIdx.x;
    const int wave = tid >> 6, lane = tid & 63;
    const int wr = wave >> 1, wc = wave & 1;
    const int l15 = lane & 15, lq = lane >> 4;

    float4_t acc[4][4];
#pragma unroll
    for (int im = 0; im < 4; im++)
#pragma unroll
        for (int in = 0; in < 4; in++)
#pragma unroll
            for (int r = 0; r < 4; r++) acc[im][in][r] = 0.f;

    for (int kt = 0; kt < ISZ; kt += 32) {
        __syncthreads();
#pragma unroll
        for (int ld = 0; ld < 2; ld++) {
            int c = tid + ld * 256;
            int r = c >> 2, ko = (c & 3) * 8;
            uint4 av = *(const uint4*)(A + (size_t)(bm * 128 + r) * ISZ + kt + ko);
            *(uint4*)(As + r * 40 + ko) = av;
            uint4 bv = *(const uint4*)(B + (size_t)(bn * 128 + r) * ISZ + kt + ko);
            *(uint4*)(Bs + r * 40 + ko) = bv;
        }
        __syncthreads();
        half8_t af[4], bf[4];
#pragma unroll
        for (int im = 0; im < 4; im++)
            af[im] = *(half8_t*)(As + (wr * 64 + im * 16 + l15) * 40 + lq * 8);
#pragma unroll
        for (int in = 0; in < 4; in++)
            bf[in] = *(half8_t*)(Bs + (wc * 64 + in * 16 + l15) * 40 + lq * 8);
#pragma unroll
        for (int im = 0; im < 4; im++)
#pragma unroll
            for (int in = 0; in < 4; in++)
                acc[im][in] = __builtin_amdgcn_mfma_f32_16x16x32_f16(af[im], bf[in], acc[im][in], 0, 0, 0);
    }
#pragma unroll
    for (int im = 0; im < 4; im++) {
        int mg = bm * 128 + wr * 64 + im * 16 + lq * 4;
#pragma unroll
        for (int in = 0; in < 4; in++) {
            int ng = bn * 128 + wc * 64 + in * 16 + l15;
            int gate = ng >> 11;
            int e = ng & 2047;
            int col2 = (e >> 3) * 32 + ((e >> 1) & 3) * 8 + gate * 2 + (e & 1);
#pragma unroll
            for (int r = 0; r < 4; r++)
                C[(size_t)(mg + r) * G4H + col2] = (_Float16)acc[im][in][r];
        }
    }
}

// ---------------- persistent LSTM recurrence ----------------
// Block b owns h[8b..8b+8). Wave g owns all 4 gates of elements {2g, 2g+1}
// (row r: gate=r>>1, elem=2g+(r&1)); each wave publishes its own
// self-validating word {tag32 | h_e1 | h_e0} to NREP replica lines in one
// 8-lane-predicated store (word broadcast to SGPR via readfirstlane).
// Consumer block b polls replica (b & 7): 32 readers/line instead of 256,
// 2x16B sc1 loads instead of 4x8B atomics => ~16x fewer same-line IC
// transactions per poll round (the prior version's hidden serial term).
// Poll rotation: wave g lane j polls block 64g+((j+b)&63).
// LDS: 64 units x 80 B (16 data dwords + 4 pad), b128 conflict-free.
__global__ __launch_bounds__(256, 1) void lstm_persist(
    const float* __restrict__ Whh,   // [G4H][HID] f32
    const float* __restrict__ b_ih, const float* __restrict__ b_hh,
    const _Float16* __restrict__ xp, // [SEQ][G4H] f16, permuted layout
    const float* __restrict__ fcw, const float* __restrict__ fcb,
    unsigned long long* __restrict__ words,  // [2][NREP][256][8]
    float* __restrict__ out) {
    const int b = blockIdx.x, tid = threadIdx.x;
    const int g = tid >> 6, lane = tid & 63;
    const int pblk = (g << 6) | ((lane + b) & 63);  // block this lane polls/stages

    __shared__ unsigned h_lds32[2][1280];  // parity x (64 units x 20 dwords)

    // --- prologue: weight slice into registers (f32 -> f16) ---
    half2_t w[8][16];
#pragma unroll
    for (int r = 0; r < 8; r++) {
        const float* wp =
            Whh + (size_t)((r >> 1) * HID + b * 8 + 2 * g + (r & 1)) * HID + lane * 32;
#pragma unroll
        for (int i = 0; i < 16; i++) {
            float2 f = *(const float2*)(wp + i * 2);
            half2_t h2;
            h2.x = (_Float16)f.x;
            h2.y = (_Float16)f.y;
            w[r][i] = h2;
        }
    }
    float bias_r = 0.f;
    if (lane < 8) {
        int row = ((lane >> 1) & 3) * HID + b * 8 + 2 * g + (lane & 1);
        bias_r = b_ih[row] + b_hh[row];
    }
    float c_reg = 0.f;  // cell state of elem 2g+(lane&1) -- valid in lanes 0,1 only

    const int s_dw = (pblk >> 2) * 20 + (pblk & 3) * 4;  // LDS stage dst (dwords)
    const int xpbase = b * 32 + g * 8;                   // + lane (lanes 0..7)
    const int rsel = b & (NREP - 1);                     // replica this block polls

    for (int t = 0; t < SEQ; ++t) {
        const unsigned ut = (unsigned)t;
        const int par = t & 1;

        // x_proj prefetch: one 64-B line per block-step (permuted layout).
        // Issued before the poll asm ("memory" clobber pins it above the loop)
        // so its HBM latency hides inside the wait window.
        float xpv = 0.f;
        if (lane < 8) xpv = (float)xp[(size_t)t * G4H + xpbase + lane];

        // poll own replica of block pblk's 4 self-validating words (32 B/lane)
        const unsigned long long* wp =
            words + ((size_t)par * NREP + rsel) * 2048 + (size_t)pblk * 8;
        uint4_t qa, qb;
        for (;;) {
            poll_load32(wp, qa, qb);
            bool ok = (qa.y >= ut) && (qa.w >= ut) && (qb.y >= ut) && (qb.w >= ut);
            if (__all(ok)) break;
            __builtin_amdgcn_s_sleep(1);
        }

        // stage 8 halves of block pblk into parity LDS buffer (one b128)
        uint4_t stg;
        stg.x = qa.x; stg.y = qa.z; stg.z = qb.x; stg.w = qb.z;
        *(uint4_t*)&h_lds32[par][s_dw] = stg;
        __syncthreads();  // the ONLY barrier: h_t fully staged

        // read slice [lane*32, lane*32+32) as 4 x b128 (80-B units, conflict-free)
        union {
            uint4_t q[4];
            half2_t h2[16];
        } hu;
        const uint4_t* hp4 = (const uint4_t*)((const char*)&h_lds32[par][0] + 80 * lane);
#pragma unroll
        for (int i = 0; i < 4; i++) hu.q[i] = hp4[i];

        // matvec: 8 rows x 32 cols per lane
        float acc[8];
#pragma unroll
        for (int r = 0; r < 8; r++) {
            float a = 0.f;
#pragma unroll
            for (int i = 0; i < 16; i++) a = DOT2(w[r][i], hu.h2[i], a);
            acc[r] = a;
        }
        // reduce: DPP xor1/2/4 on all 8 accs, select, DPP xor8, shfl 16/32
#pragma unroll
        for (int r = 0; r < 8; r++) {
            acc[r] = dpp_add<DPP_XOR1>(acc[r]);
            acc[r] = dpp_add<DPP_XOR2>(acc[r]);
            acc[r] = dpp_add<DPP_XOR4>(acc[r]);
        }
        float u;
        {
            int s = lane & 7;
            float u01 = (s & 1) ? acc[1] : acc[0];
            float u23 = (s & 1) ? acc[3] : acc[2];
            float u45 = (s & 1) ? acc[5] : acc[4];
            float u67 = (s & 1) ? acc[7] : acc[6];
            float ua = (s & 2) ? u23 : u01;
            float ub = (s & 2) ? u67 : u45;
            u = (s & 4) ? ub : ua;
        }
        u = dpp_add<DPP_XOR8>(u);
        u += __shfl_xor(u, 16, 64);
        u += __shfl_xor(u, 32, 64);
        u += bias_r + xpv;  // valid in lanes 0..7 (all DPP gathers below stay in 0..7)

        // gates: rows [i_e0,i_e1,f_e0,f_e1,g_e0,g_e1,o_e0,o_e1] in lanes 0..7.
        // DPP row_shl gathers (lanes 0,1 valid) replace 4 ds_bpermute shuffles.
        {
            float gi = u;                       // lane0: u0 (i_e0), lane1: u1 (i_e1)
            float gf = dpp_movf<DPP_SHL2>(u);   // lane0: u2, lane1: u3
            float gg = dpp_movf<DPP_SHL4>(u);   // lane0: u4, lane1: u5
            float go = dpp_movf<DPP_SHL6>(u);   // lane0: u6, lane1: u7
            float si = RCP(1.f + __expf(-gi));
            float sf = RCP(1.f + __expf(-gf));
            float so = RCP(1.f + __expf(-go));
            float tg = 1.f - 2.f * RCP(1.f + __expf(2.f * gg));
            c_reg = sf * c_reg + si * tg;       // garbage in lanes >=2: never read
            float tc = 1.f - 2.f * RCP(1.f + __expf(2.f * c_reg));
            float h = so * tc;
            _Float16 hf = (_Float16)h;
            unsigned pk = *(unsigned short*)&hf;
            unsigned pk1 = (unsigned)__builtin_amdgcn_update_dpp(
                0, (int)pk, DPP_SHL1, 0xF, 0xF, true);  // lane0 <- lane1's pk
            unsigned lo = pk | (pk1 << 16);             // valid in lane0
            unsigned lou = (unsigned)__builtin_amdgcn_readfirstlane((int)lo);
            unsigned long long wword =
                (unsigned long long)lou | ((unsigned long long)(ut + 1) << 32);
            // one 8-lane-predicated store publishes all NREP replicas at once
            unsigned long long* wb =
                words + (size_t)((t + 1) & 1) * (NREP * 2048) + (size_t)b * 8 + g;
            if (lane < NREP) st_u64(wb + (size_t)lane * 2048, wword);
        }
        // parity-double-buffered LDS + B1 ordering make cross-step reuse race-free
    }

    // --- final fc on h_SEQ (parity 0) by block 0 ---
    if (b == 0) {
        const int par = SEQ & 1;  // 0
        const unsigned long long* wp =
            words + ((size_t)par * NREP + rsel) * 2048 + (size_t)pblk * 8;
        uint4_t qa, qb;
        for (;;) {
            poll_load32(wp, qa, qb);
            bool ok = (qa.y >= (unsigned)SEQ) && (qa.w >= (unsigned)SEQ) &&
                      (qb.y >= (unsigned)SEQ) && (qb.w >= (unsigned)SEQ);
            if (__all(ok)) break;
            __builtin_amdgcn_s_sleep(1);
        }
        uint4_t stg;
        stg.x = qa.x; stg.y = qa.z; stg.z = qb.x; stg.w = qb.z;
        *(uint4_t*)&h_lds32[par][s_dw] = stg;
        __syncthreads();
        if (g == 0) {
            union {
                uint4_t q[4];
                half2_t h2[16];
            } hu;
            const uint4_t* hp4 = (const uint4_t*)((const char*)&h_lds32[par][0] + 80 * lane);
#pragma unroll
            for (int i = 0; i < 4; i++) hu.q[i] = hp4[i];
            float s = 0.f;
            const float* fw = fcw + lane * 32;
#pragma unroll
            for (int i = 0; i < 16; i++)
                s += (float)hu.h2[i].x * fw[2 * i] + (float)hu.h2[i].y * fw[2 * i + 1];
#pragma unroll
            for (int off = 1; off < 64; off <<= 1) s += __shfl_xor(s, off, 64);
            if (lane == 0) out[0] = s + fcb[0];
        }
    }
}

// ---------------- launch ----------------
extern "C" void kernel_launch(void* const* d_in, const int* in_sizes, int n_in,
                              void* d_out, int out_size, void* d_ws, size_t ws_size,
                              hipStream_t stream) {
    const float* input = (const float*)d_in[0];  // [SEQ][ISZ]
    const float* W_ih = (const float*)d_in[1];   // [G4H][ISZ]
    const float* W_hh = (const float*)d_in[2];   // [G4H][HID]
    const float* b_ih = (const float*)d_in[3];
    const float* b_hh = (const float*)d_in[4];
    const float* fc_w = (const float*)d_in[5];
    const float* fc_b = (const float*)d_in[6];
    float* out = (float*)d_out;

    char* ws = (char*)d_ws;
    _Float16* xp16 = (_Float16*)ws;               // 134,217,728 B
    _Float16* A16 = (_Float16*)(ws + 134217728);  // 8 MB (dead after gemm)
    _Float16* B16 = (_Float16*)(ws + 142606336);  // 8 MB (dead after gemm)
    // words overlay the dead A16 region (init_state runs AFTER gemm):
    unsigned long long* words = (unsigned long long*)(ws + 134217728);  // 262,144 B

    cvt_f32_f16<<<(SEQ * ISZ) / 1024, 256, 0, stream>>>(input, A16, SEQ * ISZ);
    cvt_f32_f16<<<(G4H * ISZ) / 1024, 256, 0, stream>>>(W_ih, B16, G4H * ISZ);

    dim3 gg(G4H / 128, SEQ / 128);
    gemm_xproj<<<gg, 256, 0, stream>>>(A16, B16, xp16);

    init_state<<<(2 * NREP * 2048) / 256, 256, 0, stream>>>(words);  // after gemm

    lstm_persist<<<NB, 256, 0, stream>>>(W_hh, b_ih, b_hh, xp16, fc_w, fc_b,
                                         words, out);
}

// Round 2
// 12740.411 us; speedup vs baseline: 1.1805x; 1.0122x over previous
//
#include <hip/hip_runtime.h>
#include <hip/hip_bf16.h>

// ---------------- types ----------------
typedef _Float16 half2_t __attribute__((ext_vector_type(2)));
typedef _Float16 half8_t __attribute__((ext_vector_type(8)));
typedef float float4_t __attribute__((ext_vector_type(4)));
typedef unsigned uint4_t __attribute__((ext_vector_type(4)));

#define SEQ   8192
#define ISZ   512
#define HID   2048
#define G4H   8192   // 4*HID
#define NB    256    // persistent blocks (== CU count)
#define NREP  8      // replication of published h-words (readers/line: 256 -> 32)

#if __has_builtin(__builtin_amdgcn_fdot2)
#define DOT2(a, b, c) __builtin_amdgcn_fdot2((a), (b), (c), false)
#else
static __device__ __forceinline__ float DOT2(half2_t a, half2_t b, float c) {
    return c + (float)a.x * (float)b.x + (float)a.y * (float)b.y;
}
#endif

#if __has_builtin(__builtin_amdgcn_rcpf)
#define RCP(x) __builtin_amdgcn_rcpf(x)
#else
#define RCP(x) (1.0f / (x))
#endif

// Publish one 8-B word via agent-coherent atomic swap (no return).
// Key difference vs a plain sc1 store: the atomic EXECUTES at the device
// coherence point (IC/MALL) and leaves the line valid there, instead of
// writing through to HBM. Subsequent sc1 poll loads then hit IC (~450 cyc)
// instead of missing to HBM (~900 cyc). Data+tag packed in one word keeps
// the protocol self-validating under relaxed ordering.
static __device__ __forceinline__ void pub_u64(void* p, unsigned long long v) {
    asm volatile("global_atomic_swap_x2 %0, %1, off sc1"
                 :
                 : "v"((unsigned long long*)p), "v"(v)
                 : "memory");
}

// Wide agent-coherent poll: 32 B of one 64-B line as 2 x dwordx4 with sc1
// (L2-bypass; served from IC). Each 8-B word is 16-B-aligned within a single
// line access => never torn; tags are per-word self-validating so skew
// between the two loads is harmless.
static __device__ __forceinline__ void poll_load32(const void* p, uint4_t& a,
                                                   uint4_t& b) {
    unsigned long long addr = (unsigned long long)p;
    asm volatile(
        "global_load_dwordx4 %0, %2, off sc1\n\t"
        "global_load_dwordx4 %1, %2, off offset:16 sc1\n\t"
        "s_waitcnt vmcnt(0)"
        : "=&v"(a), "=&v"(b)
        : "v"(addr)
        : "memory");
}

// DPP butterfly add: x + perm(x). Valid for reduction levels where the
// permutation crosses the current group boundary (see call sites).
template <int CTRL>
static __device__ __forceinline__ float dpp_add(float x) {
    int v = __builtin_amdgcn_update_dpp(0, __builtin_bit_cast(int, x), CTRL, 0xF,
                                        0xF, true);
    return x + __builtin_bit_cast(float, v);
}
// DPP move (no add): lane i <- lane i+N (row_shl:N), zeros past row edge.
template <int CTRL>
static __device__ __forceinline__ float dpp_movf(float x) {
    int v = __builtin_amdgcn_update_dpp(0, __builtin_bit_cast(int, x), CTRL, 0xF,
                                        0xF, true);
    return __builtin_bit_cast(float, v);
}
#define DPP_XOR1  0xB1   // quad_perm [1,0,3,2]
#define DPP_XOR2  0x4E   // quad_perm [2,3,0,1]
#define DPP_XOR4  0x141  // row_half_mirror (valid: groups of 4 uniform)
#define DPP_XOR8  0x128  // row_ror:8 (exact lane s <-> s+8 within row16)
#define DPP_SHL1  0x101  // row_shl:1
#define DPP_SHL2  0x102  // row_shl:2
#define DPP_SHL4  0x104  // row_shl:4
#define DPP_SHL6  0x106  // row_shl:6

// ---------------- f32 -> f16 convert ----------------
__global__ __launch_bounds__(256) void cvt_f32_f16(const float* __restrict__ in,
                                                   _Float16* __restrict__ out, int n) {
    int i = (blockIdx.x * 256 + threadIdx.x) * 4;
    if (i < n) {
        float4 v = *(const float4*)(in + i);
        out[i + 0] = (_Float16)v.x;
        out[i + 1] = (_Float16)v.y;
        out[i + 2] = (_Float16)v.z;
        out[i + 3] = (_Float16)v.w;
    }
}

// ---------------- init words (zero => {h=0, tag=0} == "h_0 valid") ----------------
__global__ __launch_bounds__(256) void init_state(unsigned long long* __restrict__ words) {
    int i = blockIdx.x * 256 + threadIdx.x;
    if (i < 2 * NREP * 2048) words[i] = 0ull;  // words[2][NREP][256][8]
}

// ---------------- x_proj GEMM: C = A @ B^T, epilogue scattered into xp2 ----------
// xp2 layout: xp2[t][b*32 + g*8 + r] where r = gate*2 + (elem&1), g = (elem>>1)&3,
// b = elem>>3  (elem = col & 2047, gate = col >> 11). One 64-B line per block-step.
__global__ __launch_bounds__(256) void gemm_xproj(const _Float16* __restrict__ A,  // [SEQ][ISZ]
                                                  const _Float16* __restrict__ B,  // [G4H][ISZ]
                                                  _Float16* __restrict__ C) {      // [SEQ][G4H] permuted
    __shared__ _Float16 As[128 * 40];
    __shared__ _Float16 Bs[128 * 40];
    const int tid = threadIdx.x;
    const int bm = blockIdx.y, bn = blockIdx.x;
    const int wave = tid >> 6, lane = tid & 63;
    const int wr = wave >> 1, wc = wave & 1;
    const int l15 = lane & 15, lq = lane >> 4;

    float4_t acc[4][4];
#pragma unroll
    for (int im = 0; im < 4; im++)
#pragma unroll
        for (int in = 0; in < 4; in++)
#pragma unroll
            for (int r = 0; r < 4; r++) acc[im][in][r] = 0.f;

    for (int kt = 0; kt < ISZ; kt += 32) {
        __syncthreads();
#pragma unroll
        for (int ld = 0; ld < 2; ld++) {
            int c = tid + ld * 256;
            int r = c >> 2, ko = (c & 3) * 8;
            uint4 av = *(const uint4*)(A + (size_t)(bm * 128 + r) * ISZ + kt + ko);
            *(uint4*)(As + r * 40 + ko) = av;
            uint4 bv = *(const uint4*)(B + (size_t)(bn * 128 + r) * ISZ + kt + ko);
            *(uint4*)(Bs + r * 40 + ko) = bv;
        }
        __syncthreads();
        half8_t af[4], bf[4];
#pragma unroll
        for (int im = 0; im < 4; im++)
            af[im] = *(half8_t*)(As + (wr * 64 + im * 16 + l15) * 40 + lq * 8);
#pragma unroll
        for (int in = 0; in < 4; in++)
            bf[in] = *(half8_t*)(Bs + (wc * 64 + in * 16 + l15) * 40 + lq * 8);
#pragma unroll
        for (int im = 0; im < 4; im++)
#pragma unroll
            for (int in = 0; in < 4; in++)
                acc[im][in] = __builtin_amdgcn_mfma_f32_16x16x32_f16(af[im], bf[in], acc[im][in], 0, 0, 0);
    }
#pragma unroll
    for (int im = 0; im < 4; im++) {
        int mg = bm * 128 + wr * 64 + im * 16 + lq * 4;
#pragma unroll
        for (int in = 0; in < 4; in++) {
            int ng = bn * 128 + wc * 64 + in * 16 + l15;
            int gate = ng >> 11;
            int e = ng & 2047;
            int col2 = (e >> 3) * 32 + ((e >> 1) & 3) * 8 + gate * 2 + (e & 1);
#pragma unroll
            for (int r = 0; r < 4; r++)
                C[(size_t)(mg + r) * G4H + col2] = (_Float16)acc[im][in][r];
        }
    }
}

// ---------------- persistent LSTM recurrence ----------------
// Block b owns h[8b..8b+8). Wave g owns all 4 gates of elements {2g, 2g+1}
// (row r: gate=r>>1, elem=2g+(r&1)); each wave publishes its own
// self-validating word {tag32 | h_e1 | h_e0} to NREP replica lines in one
// 8-lane-predicated atomic-swap (word broadcast to SGPR via readfirstlane).
// Atomic publish executes at IC => poll loads hit IC, not HBM (the r1
// version's write-through stores forced an HBM round trip every step:
// WRITE_SIZE 2.1 GB, FETCH_SIZE +500 MB of word re-fetches).
// Consumer block b polls replica (b & 7): 32 readers/line, 2x16B sc1 loads.
// Poll rotation: wave g lane j polls block 64g+((j+b)&63).
// LDS: 64 units x 80 B (16 data dwords + 4 pad), b128 conflict-free.
__global__ __launch_bounds__(256, 1) void lstm_persist(
    const float* __restrict__ Whh,   // [G4H][HID] f32
    const float* __restrict__ b_ih, const float* __restrict__ b_hh,
    const _Float16* __restrict__ xp, // [SEQ][G4H] f16, permuted layout
    const float* __restrict__ fcw, const float* __restrict__ fcb,
    unsigned long long* __restrict__ words,  // [2][NREP][256][8]
    float* __restrict__ out) {
    const int b = blockIdx.x, tid = threadIdx.x;
    const int g = tid >> 6, lane = tid & 63;
    const int pblk = (g << 6) | ((lane + b) & 63);  // block this lane polls/stages

    __shared__ unsigned h_lds32[2][1280];  // parity x (64 units x 20 dwords)

    // --- prologue: weight slice into registers (f32 -> f16) ---
    half2_t w[8][16];
#pragma unroll
    for (int r = 0; r < 8; r++) {
        const float* wp =
            Whh + (size_t)((r >> 1) * HID + b * 8 + 2 * g + (r & 1)) * HID + lane * 32;
#pragma unroll
        for (int i = 0; i < 16; i++) {
            float2 f = *(const float2*)(wp + i * 2);
            half2_t h2;
            h2.x = (_Float16)f.x;
            h2.y = (_Float16)f.y;
            w[r][i] = h2;
        }
    }
    float bias_r = 0.f;
    if (lane < 8) {
        int row = ((lane >> 1) & 3) * HID + b * 8 + 2 * g + (lane & 1);
        bias_r = b_ih[row] + b_hh[row];
    }
    float c_reg = 0.f;  // cell state of elem 2g+(lane&1) -- valid in lanes 0,1 only

    const int s_dw = (pblk >> 2) * 20 + (pblk & 3) * 4;  // LDS stage dst (dwords)
    const int xpbase = b * 32 + g * 8;                   // + lane (lanes 0..7)
    const int rsel = b & (NREP - 1);                     // replica this block polls

    for (int t = 0; t < SEQ; ++t) {
        const unsigned ut = (unsigned)t;
        const int par = t & 1;

        // x_proj prefetch: one 64-B line per block-step (permuted layout).
        // Issued before the poll asm ("memory" clobber pins it above the loop)
        // so its HBM latency hides inside the wait window.
        float xpv = 0.f;
        if (lane < 8) xpv = (float)xp[(size_t)t * G4H + xpbase + lane];

        // poll own replica of block pblk's 4 self-validating words (32 B/lane)
        const unsigned long long* wp =
            words + ((size_t)par * NREP + rsel) * 2048 + (size_t)pblk * 8;
        uint4_t qa, qb;
        for (;;) {
            poll_load32(wp, qa, qb);
            bool ok = (qa.y >= ut) && (qa.w >= ut) && (qb.y >= ut) && (qb.w >= ut);
            if (__all(ok)) break;
        }

        // stage 8 halves of block pblk into parity LDS buffer (one b128)
        uint4_t stg;
        stg.x = qa.x; stg.y = qa.z; stg.z = qb.x; stg.w = qb.z;
        *(uint4_t*)&h_lds32[par][s_dw] = stg;
        __syncthreads();  // the ONLY barrier: h_t fully staged

        // read slice [lane*32, lane*32+32) as 4 x b128 (80-B units, conflict-free)
        union {
            uint4_t q[4];
            half2_t h2[16];
        } hu;
        const uint4_t* hp4 = (const uint4_t*)((const char*)&h_lds32[par][0] + 80 * lane);
#pragma unroll
        for (int i = 0; i < 4; i++) hu.q[i] = hp4[i];

        // matvec: 8 rows x 32 cols per lane
        float acc[8];
#pragma unroll
        for (int r = 0; r < 8; r++) {
            float a = 0.f;
#pragma unroll
            for (int i = 0; i < 16; i++) a = DOT2(w[r][i], hu.h2[i], a);
            acc[r] = a;
        }
        // reduce: DPP xor1/2/4 on all 8 accs, select, DPP xor8, shfl 16/32
#pragma unroll
        for (int r = 0; r < 8; r++) {
            acc[r] = dpp_add<DPP_XOR1>(acc[r]);
            acc[r] = dpp_add<DPP_XOR2>(acc[r]);
            acc[r] = dpp_add<DPP_XOR4>(acc[r]);
        }
        float u;
        {
            int s = lane & 7;
            float u01 = (s & 1) ? acc[1] : acc[0];
            float u23 = (s & 1) ? acc[3] : acc[2];
            float u45 = (s & 1) ? acc[5] : acc[4];
            float u67 = (s & 1) ? acc[7] : acc[6];
            float ua = (s & 2) ? u23 : u01;
            float ub = (s & 2) ? u67 : u45;
            u = (s & 4) ? ub : ua;
        }
        u = dpp_add<DPP_XOR8>(u);
        u += __shfl_xor(u, 16, 64);
        u += __shfl_xor(u, 32, 64);
        u += bias_r + xpv;  // valid in lanes 0..7 (all DPP gathers below stay in 0..7)

        // gates: rows [i_e0,i_e1,f_e0,f_e1,g_e0,g_e1,o_e0,o_e1] in lanes 0..7.
        // DPP row_shl gathers (lanes 0,1 valid) replace ds_bpermute shuffles.
        {
            float gi = u;                       // lane0: u0 (i_e0), lane1: u1 (i_e1)
            float gf = dpp_movf<DPP_SHL2>(u);   // lane0: u2, lane1: u3
            float gg = dpp_movf<DPP_SHL4>(u);   // lane0: u4, lane1: u5
            float go = dpp_movf<DPP_SHL6>(u);   // lane0: u6, lane1: u7
            float si = RCP(1.f + __expf(-gi));
            float sf = RCP(1.f + __expf(-gf));
            float so = RCP(1.f + __expf(-go));
            float tg = 1.f - 2.f * RCP(1.f + __expf(2.f * gg));
            c_reg = sf * c_reg + si * tg;       // garbage in lanes >=2: never read
            float tc = 1.f - 2.f * RCP(1.f + __expf(2.f * c_reg));
            float h = so * tc;
            _Float16 hf = (_Float16)h;
            unsigned pk = *(unsigned short*)&hf;
            unsigned pk1 = (unsigned)__builtin_amdgcn_update_dpp(
                0, (int)pk, DPP_SHL1, 0xF, 0xF, true);  // lane0 <- lane1's pk
            unsigned lo = pk | (pk1 << 16);             // valid in lane0
            unsigned lou = (unsigned)__builtin_amdgcn_readfirstlane((int)lo);
            unsigned long long wword =
                (unsigned long long)lou | ((unsigned long long)(ut + 1) << 32);
            // one 8-lane-predicated atomic publishes all NREP replicas at once;
            // atomic executes at IC => line stays IC-resident for pollers.
            unsigned long long* wb =
                words + (size_t)((t + 1) & 1) * (NREP * 2048) + (size_t)b * 8 + g;
            if (lane < NREP) pub_u64(wb + (size_t)lane * 2048, wword);
        }
        // parity-double-buffered LDS + B1 ordering make cross-step reuse race-free
    }

    // --- final fc on h_SEQ (parity 0) by block 0 ---
    if (b == 0) {
        const int par = SEQ & 1;  // 0
        const unsigned long long* wp =
            words + ((size_t)par * NREP + rsel) * 2048 + (size_t)pblk * 8;
        uint4_t qa, qb;
        for (;;) {
            poll_load32(wp, qa, qb);
            bool ok = (qa.y >= (unsigned)SEQ) && (qa.w >= (unsigned)SEQ) &&
                      (qb.y >= (unsigned)SEQ) && (qb.w >= (unsigned)SEQ);
            if (__all(ok)) break;
            __builtin_amdgcn_s_sleep(1);
        }
        uint4_t stg;
        stg.x = qa.x; stg.y = qa.z; stg.z = qb.x; stg.w = qb.z;
        *(uint4_t*)&h_lds32[par][s_dw] = stg;
        __syncthreads();
        if (g == 0) {
            union {
                uint4_t q[4];
                half2_t h2[16];
            } hu;
            const uint4_t* hp4 = (const uint4_t*)((const char*)&h_lds32[par][0] + 80 * lane);
#pragma unroll
            for (int i = 0; i < 4; i++) hu.q[i] = hp4[i];
            float s = 0.f;
            const float* fw = fcw + lane * 32;
#pragma unroll
            for (int i = 0; i < 16; i++)
                s += (float)hu.h2[i].x * fw[2 * i] + (float)hu.h2[i].y * fw[2 * i + 1];
#pragma unroll
            for (int off = 1; off < 64; off <<= 1) s += __shfl_xor(s, off, 64);
            if (lane == 0) out[0] = s + fcb[0];
        }
    }
}

// ---------------- launch ----------------
extern "C" void kernel_launch(void* const* d_in, const int* in_sizes, int n_in,
                              void* d_out, int out_size, void* d_ws, size_t ws_size,
                              hipStream_t stream) {
    const float* input = (const float*)d_in[0];  // [SEQ][ISZ]
    const float* W_ih = (const float*)d_in[1];   // [G4H][ISZ]
    const float* W_hh = (const float*)d_in[2];   // [G4H][HID]
    const float* b_ih = (const float*)d_in[3];
    const float* b_hh = (const float*)d_in[4];
    const float* fc_w = (const float*)d_in[5];
    const float* fc_b = (const float*)d_in[6];
    float* out = (float*)d_out;

    char* ws = (char*)d_ws;
    _Float16* xp16 = (_Float16*)ws;               // 134,217,728 B
    _Float16* A16 = (_Float16*)(ws + 134217728);  // 8 MB (dead after gemm)
    _Float16* B16 = (_Float16*)(ws + 142606336);  // 8 MB (dead after gemm)
    // words overlay the dead A16 region (init_state runs AFTER gemm):
    unsigned long long* words = (unsigned long long*)(ws + 134217728);  // 262,144 B

    cvt_f32_f16<<<(SEQ * ISZ) / 1024, 256, 0, stream>>>(input, A16, SEQ * ISZ);
    cvt_f32_f16<<<(G4H * ISZ) / 1024, 256, 0, stream>>>(W_ih, B16, G4H * ISZ);

    dim3 gg(G4H / 128, SEQ / 128);
    gemm_xproj<<<gg, 256, 0, stream>>>(A16, B16, xp16);

    init_state<<<(2 * NREP * 2048) / 256, 256, 0, stream>>>(words);  // after gemm

    lstm_persist<<<NB, 256, 0, stream>>>(W_hh, b_ih, b_hh, xp16, fc_w, fc_b,
                                         words, out);
}